// Round 11
// baseline (538.543 us; speedup 1.0000x reference)
//
#include <hip/hip_runtime.h>

#define HD 128
#define BN_EPS 1e-5f

typedef unsigned int uint;
typedef unsigned short ushort;
typedef __attribute__((ext_vector_type(8))) short short8;
typedef __attribute__((ext_vector_type(4))) float f32x4;

union U4S8 { uint4 u; short8 s; };

// bf16x2 packed in a uint: lo half = even feature, hi half = odd feature
__device__ __forceinline__ float bf_lo(uint u) { return __uint_as_float(u << 16); }
__device__ __forceinline__ float bf_hi(uint u) { return __uint_as_float(u & 0xffff0000u); }
__device__ __forceinline__ uint bf_round(float f) {  // RNE to bf16 bits (in high 16)
    uint u = __float_as_uint(f);
    return (u + 0x7fffu + ((u >> 16) & 1u)) & 0xffff0000u;
}
__device__ __forceinline__ uint pack_bf2(float a, float b) {
    return (bf_round(a) >> 16) | bf_round(b);
}
__device__ __forceinline__ void unpack8(uint4 u, float* f) {
    f[0] = bf_lo(u.x); f[1] = bf_hi(u.x);
    f[2] = bf_lo(u.y); f[3] = bf_hi(u.y);
    f[4] = bf_lo(u.z); f[5] = bf_hi(u.z);
    f[6] = bf_lo(u.w); f[7] = bf_hi(u.w);
}

// ---------------- CSR build ----------------

__global__ __launch_bounds__(256) void k_count(const int* __restrict__ dst, int* __restrict__ cnt, int E) {
    int e = blockIdx.x * 256 + threadIdx.x;
    if (e < E) atomicAdd(&cnt[dst[e]], 1);
}

// block partial sums over 1024-element chunks; also computes dinv
__global__ __launch_bounds__(256) void k_scan_a(const int* __restrict__ cnt, int* __restrict__ bsum,
                                                float* __restrict__ dinv, int N) {
    __shared__ int s[256];
    int base = blockIdx.x * 1024 + threadIdx.x * 4;
    int v = 0;
#pragma unroll
    for (int j = 0; j < 4; ++j) {
        int idx = base + j;
        if (idx < N) {
            int c = cnt[idx];
            v += c;
            dinv[idx] = rsqrtf((float)c + 1.0f);
        }
    }
    s[threadIdx.x] = v;
    __syncthreads();
    for (int o = 128; o; o >>= 1) {
        if (threadIdx.x < (unsigned)o) s[threadIdx.x] += s[threadIdx.x + o];
        __syncthreads();
    }
    if (threadIdx.x == 0) bsum[blockIdx.x] = s[0];
}

// parallel exclusive scan of block sums (NB <= 1024)
__global__ __launch_bounds__(256) void k_scan_b(int* __restrict__ bsum, int NB) {
    __shared__ int s[256];
    const int t = threadIdx.x;
    int v[4];
    int ts = 0;
#pragma unroll
    for (int j = 0; j < 4; ++j) {
        int i = t * 4 + j;
        v[j] = (i < NB) ? bsum[i] : 0;
        ts += v[j];
    }
    s[t] = ts;
    __syncthreads();
    for (int o = 1; o < 256; o <<= 1) {
        int add = (t >= o) ? s[t - o] : 0;
        __syncthreads();
        s[t] += add;
        __syncthreads();
    }
    int excl = s[t] - ts;
#pragma unroll
    for (int j = 0; j < 4; ++j) {
        int i = t * 4 + j;
        if (i < NB) bsum[i] = excl;
        excl += v[j];
    }
}

// per-chunk exclusive scan + block offset -> rowptr AND cursor (fill bumps cursor to row end)
__global__ __launch_bounds__(256) void k_scan_c(const int* __restrict__ cnt, const int* __restrict__ bsum,
                                                int* __restrict__ rowptr, int* __restrict__ cursor, int N) {
    __shared__ int s[256];
    const int t = threadIdx.x;
    int base = blockIdx.x * 1024 + t * 4;
    int v0 = 0, v1 = 0, v2 = 0, v3 = 0;
    if (base + 0 < N) v0 = cnt[base + 0];
    if (base + 1 < N) v1 = cnt[base + 1];
    if (base + 2 < N) v2 = cnt[base + 2];
    if (base + 3 < N) v3 = cnt[base + 3];
    int ts = v0 + v1 + v2 + v3;
    s[t] = ts;
    __syncthreads();
    for (int o = 1; o < 256; o <<= 1) {
        int add = (t >= o) ? s[t - o] : 0;
        __syncthreads();
        s[t] += add;
        __syncthreads();
    }
    int excl = s[t] - ts + bsum[blockIdx.x];
    int p0 = excl, p1 = excl + v0, p2 = excl + v0 + v1, p3 = excl + v0 + v1 + v2;
    if (base + 0 < N) { rowptr[base + 0] = p0; cursor[base + 0] = p0; }
    if (base + 1 < N) { rowptr[base + 1] = p1; cursor[base + 1] = p1; }
    if (base + 2 < N) { rowptr[base + 2] = p2; cursor[base + 2] = p2; }
    if (base + 3 < N) { rowptr[base + 3] = p3; cursor[base + 3] = p3; }
}

// cursor starts as copy of rowptr; fill bumps it to row end (verbatim r6)
__global__ __launch_bounds__(256) void k_fill(const int* __restrict__ src, const int* __restrict__ dst,
                                              const float* __restrict__ dinv, int* __restrict__ cursor,
                                              int* __restrict__ csr_src, float* __restrict__ csr_w, int E) {
    int e = blockIdx.x * 256 + threadIdx.x;
    if (e >= E) return;
    int s = src[e], d = dst[e];
    int pos = atomicAdd(&cursor[d], 1);
    csr_src[pos] = s;
    csr_w[pos] = dinv[s] * dinv[d];
}

// ---------------- W prep (all 3 layers): wb[l][col][k] = bf16(W_l[k][col]) ----------------

__global__ __launch_bounds__(256) void k_wprep3(const float* __restrict__ W0, const float* __restrict__ W1,
                                                const float* __restrict__ W2, ushort* __restrict__ wb) {
    int t = blockIdx.x * 256 + threadIdx.x;  // 49152 = 3*128*128
    int m = t >> 14;
    int i = t & 16383;
    const float* W = (m == 0) ? W0 : ((m == 1) ? W1 : W2);
    int k = i >> 7, col = i & 127;
    wb[m * 16384 + col * 128 + k] = (ushort)(bf_round(W[i]) >> 16);
}

// ---------------- MFMA GEMM: C_bf16[N,128] = bn_relu(A)[N,128] @ W ----------------
// IN_BF16 path computes the previous layer's BN scale/shift from stats in LDS (fused bn_fin).
// MFMA operands swapped (W-frag as A, row-frag as B) so D is transposed: lane owns one C-row
// and 4 consecutive C-cols per reg -> shfl-free epilogue with uint2 stores.

template <int IN_BF16>
__global__ __launch_bounds__(256) void k_mm(const void* __restrict__ Ain, const uint4* __restrict__ wb4,
                                            uint* __restrict__ C, int N, const float* __restrict__ stats,
                                            const float* __restrict__ gg, const float* __restrict__ be,
                                            float invN) {
    __shared__ uint4 wl[2048];  // 32KB: idx = col*16 + kk*4 + g, stored at idx ^ ((idx>>4)&7)
    __shared__ float scshs[256];
    const int t = threadIdx.x;
#pragma unroll
    for (int i = 0; i < 8; ++i) {
        int idx = i * 256 + t;
        wl[idx ^ ((idx >> 4) & 7)] = wb4[idx];
    }
    if (IN_BF16 && t < 128) {
        float mean = stats[t] * invN;
        float var = fmaf(-mean, mean, stats[HD + t] * invN);
        float sc = gg[t] * rsqrtf(var + BN_EPS);
        scshs[t] = sc;
        scshs[HD + t] = fmaf(-mean, sc, be[t]);
    }
    __syncthreads();

    const int l = t & 63;
    const int w = t >> 6;
    const int r = l & 15;
    const int g = l >> 4;
    const int rbase = blockIdx.x * 128 + w * 32;

    short8 a[2][4];
#pragma unroll
    for (int tt = 0; tt < 2; ++tt) {
        int row = rbase + tt * 16 + r;
        bool ok = row < N;
#pragma unroll
        for (int kk = 0; kk < 4; ++kk) {
            U4S8 v;
            v.u = make_uint4(0u, 0u, 0u, 0u);
            if (ok) {
                if (IN_BF16) {
                    uint4 ld = ((const uint4*)Ain)[(size_t)row * 16 + kk * 4 + g];
                    float f[8];
                    unpack8(ld, f);
                    const float4 sc0 = *(const float4*)&scshs[(kk * 8 + g * 2) * 4];
                    const float4 sc1 = *(const float4*)&scshs[(kk * 8 + g * 2 + 1) * 4];
                    const float4 sh0 = *(const float4*)&scshs[HD + (kk * 8 + g * 2) * 4];
                    const float4 sh1 = *(const float4*)&scshs[HD + (kk * 8 + g * 2 + 1) * 4];
                    f[0] = fmaxf(fmaf(f[0], sc0.x, sh0.x), 0.f);
                    f[1] = fmaxf(fmaf(f[1], sc0.y, sh0.y), 0.f);
                    f[2] = fmaxf(fmaf(f[2], sc0.z, sh0.z), 0.f);
                    f[3] = fmaxf(fmaf(f[3], sc0.w, sh0.w), 0.f);
                    f[4] = fmaxf(fmaf(f[4], sc1.x, sh1.x), 0.f);
                    f[5] = fmaxf(fmaf(f[5], sc1.y, sh1.y), 0.f);
                    f[6] = fmaxf(fmaf(f[6], sc1.z, sh1.z), 0.f);
                    f[7] = fmaxf(fmaf(f[7], sc1.w, sh1.w), 0.f);
                    v.u.x = pack_bf2(f[0], f[1]);
                    v.u.y = pack_bf2(f[2], f[3]);
                    v.u.z = pack_bf2(f[4], f[5]);
                    v.u.w = pack_bf2(f[6], f[7]);
                } else {
                    const float4* A4 = (const float4*)Ain;
                    float4 x0 = A4[(size_t)row * 32 + kk * 8 + g * 2];
                    float4 x1 = A4[(size_t)row * 32 + kk * 8 + g * 2 + 1];
                    v.u.x = pack_bf2(x0.x, x0.y);
                    v.u.y = pack_bf2(x0.z, x0.w);
                    v.u.z = pack_bf2(x1.x, x1.y);
                    v.u.w = pack_bf2(x1.z, x1.w);
                }
            }
            a[tt][kk] = v.s;
        }
    }

    f32x4 acc[2][8];
#pragma unroll
    for (int tt = 0; tt < 2; ++tt)
#pragma unroll
        for (int c = 0; c < 8; ++c) acc[tt][c] = (f32x4){0.f, 0.f, 0.f, 0.f};

#pragma unroll
    for (int c = 0; c < 8; ++c) {
#pragma unroll
        for (int kk = 0; kk < 4; ++kk) {
            int idx = (c * 16 + r) * 16 + kk * 4 + g;
            U4S8 b;
            b.u = wl[idx ^ ((idx >> 4) & 7)];
            // swapped operands: D layout transposed (lane: C-row = l&15, 4 C-cols = g*4+reg)
            acc[0][c] = __builtin_amdgcn_mfma_f32_16x16x32_bf16(b.s, a[0][kk], acc[0][c], 0, 0, 0);
            acc[1][c] = __builtin_amdgcn_mfma_f32_16x16x32_bf16(b.s, a[1][kk], acc[1][c], 0, 0, 0);
        }
    }

    // epilogue: lane packs its own 4 consecutive cols -> one uint2 store per (tt,c), no shfl
#pragma unroll
    for (int tt = 0; tt < 2; ++tt) {
        int row = rbase + tt * 16 + r;
        if (row < N) {
#pragma unroll
            for (int c = 0; c < 8; ++c) {
                uint2 p;
                p.x = pack_bf2(acc[tt][c][0], acc[tt][c][1]);
                p.y = pack_bf2(acc[tt][c][2], acc[tt][c][3]);
                *(uint2*)&C[(size_t)row * 64 + c * 8 + g * 2] = p;
            }
        }
    }
}

// ---------------- fused aggregation (VERBATIM r6-benched: 84us, VGPR 32) ----------------
// wave layout: slot s = lane&15 (features 8s..8s+7, one uint4), quarter q = lane>>4.
// virtual edge 0 = self-loop (w = dinv^2); virtual edges 1..deg = CSR edges.

#define GATHER_BLOCKS 4096

__global__ __launch_bounds__(256) void k_gather(const uint4* __restrict__ hW4, const int* __restrict__ rowptr,
                                                const int* __restrict__ rowend, const int* __restrict__ csr_src,
                                                const float* __restrict__ csr_w, const float* __restrict__ dinv,
                                                const float* __restrict__ bias, uint4* __restrict__ agg4,
                                                float* __restrict__ stats, int N) {
    const int l = threadIdx.x & 63;
    const int s = l & 15;
    const int q = l >> 4;
    const int wv = threadIdx.x >> 6;
    const int wid0 = blockIdx.x * 4 + wv;
    const int wstride = gridDim.x * 4;

    float bj[8];
    {
        const float4 b0 = ((const float4*)bias)[s * 2];
        const float4 b1 = ((const float4*)bias)[s * 2 + 1];
        bj[0] = b0.x; bj[1] = b0.y; bj[2] = b0.z; bj[3] = b0.w;
        bj[4] = b1.x; bj[5] = b1.y; bj[6] = b1.z; bj[7] = b1.w;
    }

    float ssum[8] = {0, 0, 0, 0, 0, 0, 0, 0};
    float ssq[8] = {0, 0, 0, 0, 0, 0, 0, 0};

    for (int n = wid0; n < N; n += wstride) {
        float sw = dinv[n];
        sw *= sw;
        const int rp = rowptr[n];
        const int re = rowend[n];
        const int deg1 = re - rp + 1;  // virtual edges: self + deg

        float a[8];
#pragma unroll
        for (int j = 0; j < 8; ++j) a[j] = (q == 0) ? bj[j] : 0.f;

        // prefetch first virtual edge for this lane group
        int idx = n;
        float w = 0.f;
        {
            int vi = q;
            if (vi == 0) { w = sw; }
            else if (vi < deg1) { int ei = rp + vi - 1; idx = csr_src[ei]; w = csr_w[ei]; }
        }
        int base = 0;
        while (true) {
            uint4 r4 = hW4[(size_t)idx * 16 + s];
            int base2 = base + 4;
            int idx2 = n;
            float w2 = 0.f;
            const bool more = base2 < deg1;
            if (more) {
                int vi = base2 + q;
                if (vi < deg1) { int ei = rp + vi - 1; idx2 = csr_src[ei]; w2 = csr_w[ei]; }
            }
            float f[8];
            unpack8(r4, f);
#pragma unroll
            for (int j = 0; j < 8; ++j) a[j] = fmaf(f[j], w, a[j]);
            if (!more) break;
            base = base2; idx = idx2; w = w2;
        }

        // cross-quarter reduce (4 partials per feature slot)
#pragma unroll
        for (int j = 0; j < 8; ++j) {
            float v = a[j];
            v += __shfl_xor(v, 16);
            v += __shfl_xor(v, 32);
            a[j] = v;
        }
        if (q == 0) {
            uint4 o;
            o.x = pack_bf2(a[0], a[1]);
            o.y = pack_bf2(a[2], a[3]);
            o.z = pack_bf2(a[4], a[5]);
            o.w = pack_bf2(a[6], a[7]);
            agg4[(size_t)n * 16 + s] = o;
        }
#pragma unroll
        for (int j = 0; j < 8; ++j) {
            ssum[j] += a[j];
            ssq[j] = fmaf(a[j], a[j], ssq[j]);
        }
    }

    __shared__ float red[2][4][16][8];
    if (q == 0) {
#pragma unroll
        for (int j = 0; j < 8; ++j) {
            red[0][wv][s][j] = ssum[j];
            red[1][wv][s][j] = ssq[j];
        }
    }
    __syncthreads();
    const int t = threadIdx.x;
    const int f = t & 127, half = t >> 7;
    float v = red[half][0][f >> 3][f & 7] + red[half][1][f >> 3][f & 7] +
              red[half][2][f >> 3][f & 7] + red[half][3][f >> 3][f & 7];
    unsafeAtomicAdd(&stats[half * HD + f], v);
}

// ---------------- decode: 2 queries per wave, 4 rows per load instruction; BN fused from stats ----

__global__ __launch_bounds__(256) void k_decode(const uint4* __restrict__ h4, const float* __restrict__ stats,
                                                const float* __restrict__ gg, const float* __restrict__ be,
                                                float invN, const int* __restrict__ qu,
                                                const int* __restrict__ qv, float* __restrict__ out, int Q) {
    __shared__ float scshs[256];
    const int t = threadIdx.x;
    if (t < 128) {
        float mean = stats[t] * invN;
        float var = fmaf(-mean, mean, stats[HD + t] * invN);
        float sc = gg[t] * rsqrtf(var + BN_EPS);
        scshs[t] = sc;
        scshs[HD + t] = fmaf(-mean, sc, be[t]);
    }
    __syncthreads();

    int tid = blockIdx.x * 256 + t;
    int wid = tid >> 6;
    int l = t & 63;
    int h = l >> 5, r = (l >> 4) & 1, s = l & 15;
    int qi = wid * 2 + h;
    if (qi >= Q) return;
    int node = r ? qv[qi] : qu[qi];
    uint4 row = h4[(size_t)node * 16 + s];

    float sc[8], sh[8];
    {
        const float4 c0 = *(const float4*)&scshs[s * 8];
        const float4 c1 = *(const float4*)&scshs[s * 8 + 4];
        const float4 h0 = *(const float4*)&scshs[HD + s * 8];
        const float4 h1 = *(const float4*)&scshs[HD + s * 8 + 4];
        sc[0] = c0.x; sc[1] = c0.y; sc[2] = c0.z; sc[3] = c0.w;
        sc[4] = c1.x; sc[5] = c1.y; sc[6] = c1.z; sc[7] = c1.w;
        sh[0] = h0.x; sh[1] = h0.y; sh[2] = h0.z; sh[3] = h0.w;
        sh[4] = h1.x; sh[5] = h1.y; sh[6] = h1.z; sh[7] = h1.w;
    }

    float own[8], oth[8];
    unpack8(row, own);
    uint4 p;
    p.x = __shfl_xor((int)row.x, 16);
    p.y = __shfl_xor((int)row.y, 16);
    p.z = __shfl_xor((int)row.z, 16);
    p.w = __shfl_xor((int)row.w, 16);
    unpack8(p, oth);

    float dot = 0.f;
#pragma unroll
    for (int j = 0; j < 8; ++j) {
        float a = fmaf(own[j], sc[j], sh[j]);
        float b = fmaf(oth[j], sc[j], sh[j]);
        dot = fmaf(a, b, dot);
    }
    dot += __shfl_xor(dot, 1);
    dot += __shfl_xor(dot, 2);
    dot += __shfl_xor(dot, 4);
    dot += __shfl_xor(dot, 8);
    if ((l & 31) == 0) out[qi] = dot;
}

// ---------------- launch ----------------

static inline size_t alignup(size_t x) { return (x + 511) & ~(size_t)511; }

extern "C" void kernel_launch(void* const* d_in, const int* in_sizes, int n_in,
                              void* d_out, int out_size, void* d_ws, size_t ws_size,
                              hipStream_t stream) {
    const float* x     = (const float*)d_in[0];
    const float* Wl[3]  = {(const float*)d_in[1], (const float*)d_in[5], (const float*)d_in[9]};
    const float* bl[3]  = {(const float*)d_in[2], (const float*)d_in[6], (const float*)d_in[10]};
    const float* gl[3]  = {(const float*)d_in[3], (const float*)d_in[7], (const float*)d_in[11]};
    const float* bel[3] = {(const float*)d_in[4], (const float*)d_in[8], (const float*)d_in[12]};
    const int* ei  = (const int*)d_in[13];
    const int* eli = (const int*)d_in[14];

    const int N = in_sizes[0] / HD;
    const int E = in_sizes[13] / 2;
    const int Q = in_sizes[14] / 2;
    const int* src = ei;
    const int* dst = ei + E;
    const int* qu = eli;
    const int* qv = eli + Q;
    float* out = (float*)d_out;

    char* ws = (char*)d_ws;
    size_t off = 0;
    float* dinv    = (float*)(ws + off); off = alignup(off + (size_t)N * 4);
    // cnt and stats3 contiguous -> one memset clears both
    int*   cnt     = (int*)(ws + off);
    float* stats3  = (float*)(ws + off + (size_t)N * 4);
    const size_t zbytes = (size_t)N * 4 + 768 * 4;
    off = alignup(off + zbytes);
    int*   rowptr  = (int*)(ws + off);   off = alignup(off + (size_t)N * 4);
    int*   cursor  = (int*)(ws + off);   off = alignup(off + (size_t)N * 4);
    int*   bsum    = (int*)(ws + off);   off = alignup(off + 1024 * 4);
    ushort* wb     = (ushort*)(ws + off); off = alignup(off + 3 * 128 * 128 * 2);
    int*   csr_src = (int*)(ws + off);   off = alignup(off + (size_t)E * 4);
    float* csr_w   = (float*)(ws + off); off = alignup(off + (size_t)E * 4);
    uint*  hB      = (uint*)(ws + off);  off = alignup(off + (size_t)N * HD * 2);  // bf16 gemm out
    uint*  hA      = (uint*)(ws + off);  off = alignup(off + (size_t)N * HD * 2);  // bf16 agg out
    (void)ws_size; (void)n_in; (void)out_size;

    const float invN = 1.0f / (float)N;
    const int NB = (N + 1023) / 1024;
    const int eg = (E + 255) / 256;

    // ---- CSR build + weight prep ----
    hipMemsetAsync(cnt, 0, zbytes, stream);
    k_count<<<eg, 256, 0, stream>>>(dst, cnt, E);
    k_scan_a<<<NB, 256, 0, stream>>>(cnt, bsum, dinv, N);
    k_scan_b<<<1, 256, 0, stream>>>(bsum, NB);
    k_scan_c<<<NB, 256, 0, stream>>>(cnt, bsum, rowptr, cursor, N);
    k_fill<<<eg, 256, 0, stream>>>(src, dst, dinv, cursor, csr_src, csr_w, E);
    k_wprep3<<<192, 256, 0, stream>>>(Wl[0], Wl[1], Wl[2], wb);

    // ---- 3 GCN layers ----
    const int mmg = (N + 127) / 128;
    for (int l = 0; l < 3; ++l) {
        const uint4* wbl = (const uint4*)(wb + (size_t)l * 16384);
        if (l == 0)
            k_mm<0><<<mmg, 256, 0, stream>>>(x, wbl, hB, N, nullptr, nullptr, nullptr, 0.f);
        else
            k_mm<1><<<mmg, 256, 0, stream>>>(hA, wbl, hB, N, stats3 + (l - 1) * 256,
                                             gl[l - 1], bel[l - 1], invN);
        k_gather<<<GATHER_BLOCKS, 256, 0, stream>>>((const uint4*)hB, rowptr, cursor, csr_src, csr_w,
                                                    dinv, bl[l], (uint4*)hA, stats3 + l * 256, N);
    }

    const int dw = (Q + 1) / 2;  // decode waves (2 queries each)
    k_decode<<<(dw + 3) / 4, 256, 0, stream>>>((const uint4*)hA, stats3 + 512, gl[2], bel[2], invN,
                                               qu, qv, out, Q);
}

// Round 12
// 425.869 us; speedup vs baseline: 1.2646x; 1.2646x over previous
//
#include <hip/hip_runtime.h>

#define HD 128
#define BN_EPS 1e-5f

typedef unsigned int uint;
typedef unsigned short ushort;
typedef __attribute__((ext_vector_type(8))) short short8;
typedef __attribute__((ext_vector_type(4))) float f32x4;

union U4S8 { uint4 u; short8 s; };

// bf16x2 packed in a uint: lo half = even feature, hi half = odd feature
__device__ __forceinline__ float bf_lo(uint u) { return __uint_as_float(u << 16); }
__device__ __forceinline__ float bf_hi(uint u) { return __uint_as_float(u & 0xffff0000u); }
__device__ __forceinline__ uint bf_round(float f) {  // RNE to bf16 bits (in high 16)
    uint u = __float_as_uint(f);
    return (u + 0x7fffu + ((u >> 16) & 1u)) & 0xffff0000u;
}
__device__ __forceinline__ uint pack_bf2(float a, float b) {
    return (bf_round(a) >> 16) | bf_round(b);
}
__device__ __forceinline__ void unpack8(uint4 u, float* f) {
    f[0] = bf_lo(u.x); f[1] = bf_hi(u.x);
    f[2] = bf_lo(u.y); f[3] = bf_hi(u.y);
    f[4] = bf_lo(u.z); f[5] = bf_hi(u.z);
    f[6] = bf_lo(u.w); f[7] = bf_hi(u.w);
}

// ---------------- CSR build ----------------

__global__ __launch_bounds__(256) void k_count(const int* __restrict__ dst, int* __restrict__ cnt, int E) {
    int e = blockIdx.x * 256 + threadIdx.x;
    if (e < E) atomicAdd(&cnt[dst[e]], 1);
}

// block partial sums over 1024-element chunks; also computes dinv
__global__ __launch_bounds__(256) void k_scan_a(const int* __restrict__ cnt, int* __restrict__ bsum,
                                                float* __restrict__ dinv, int N) {
    __shared__ int s[256];
    int base = blockIdx.x * 1024 + threadIdx.x * 4;
    int v = 0;
#pragma unroll
    for (int j = 0; j < 4; ++j) {
        int idx = base + j;
        if (idx < N) {
            int c = cnt[idx];
            v += c;
            dinv[idx] = rsqrtf((float)c + 1.0f);
        }
    }
    s[threadIdx.x] = v;
    __syncthreads();
    for (int o = 128; o; o >>= 1) {
        if (threadIdx.x < (unsigned)o) s[threadIdx.x] += s[threadIdx.x + o];
        __syncthreads();
    }
    if (threadIdx.x == 0) bsum[blockIdx.x] = s[0];
}

// parallel exclusive scan of block sums (NB <= 1024)
__global__ __launch_bounds__(256) void k_scan_b(int* __restrict__ bsum, int NB) {
    __shared__ int s[256];
    const int t = threadIdx.x;
    int v[4];
    int ts = 0;
#pragma unroll
    for (int j = 0; j < 4; ++j) {
        int i = t * 4 + j;
        v[j] = (i < NB) ? bsum[i] : 0;
        ts += v[j];
    }
    s[t] = ts;
    __syncthreads();
    for (int o = 1; o < 256; o <<= 1) {
        int add = (t >= o) ? s[t - o] : 0;
        __syncthreads();
        s[t] += add;
        __syncthreads();
    }
    int excl = s[t] - ts;
#pragma unroll
    for (int j = 0; j < 4; ++j) {
        int i = t * 4 + j;
        if (i < NB) bsum[i] = excl;
        excl += v[j];
    }
}

// per-chunk exclusive scan + block offset -> rowptr AND cursor (fill bumps cursor to row end)
__global__ __launch_bounds__(256) void k_scan_c(const int* __restrict__ cnt, const int* __restrict__ bsum,
                                                int* __restrict__ rowptr, int* __restrict__ cursor, int N) {
    __shared__ int s[256];
    const int t = threadIdx.x;
    int base = blockIdx.x * 1024 + t * 4;
    int v0 = 0, v1 = 0, v2 = 0, v3 = 0;
    if (base + 0 < N) v0 = cnt[base + 0];
    if (base + 1 < N) v1 = cnt[base + 1];
    if (base + 2 < N) v2 = cnt[base + 2];
    if (base + 3 < N) v3 = cnt[base + 3];
    int ts = v0 + v1 + v2 + v3;
    s[t] = ts;
    __syncthreads();
    for (int o = 1; o < 256; o <<= 1) {
        int add = (t >= o) ? s[t - o] : 0;
        __syncthreads();
        s[t] += add;
        __syncthreads();
    }
    int excl = s[t] - ts + bsum[blockIdx.x];
    int p0 = excl, p1 = excl + v0, p2 = excl + v0 + v1, p3 = excl + v0 + v1 + v2;
    if (base + 0 < N) { rowptr[base + 0] = p0; cursor[base + 0] = p0; }
    if (base + 1 < N) { rowptr[base + 1] = p1; cursor[base + 1] = p1; }
    if (base + 2 < N) { rowptr[base + 2] = p2; cursor[base + 2] = p2; }
    if (base + 3 < N) { rowptr[base + 3] = p3; cursor[base + 3] = p3; }
}

// cursor starts as copy of rowptr; fill bumps it to row end (verbatim r6)
__global__ __launch_bounds__(256) void k_fill(const int* __restrict__ src, const int* __restrict__ dst,
                                              const float* __restrict__ dinv, int* __restrict__ cursor,
                                              int* __restrict__ csr_src, float* __restrict__ csr_w, int E) {
    int e = blockIdx.x * 256 + threadIdx.x;
    if (e >= E) return;
    int s = src[e], d = dst[e];
    int pos = atomicAdd(&cursor[d], 1);
    csr_src[pos] = s;
    csr_w[pos] = dinv[s] * dinv[d];
}

// ---------------- W prep (all 3 layers): wb[l][col][k] = bf16(W_l[k][col]) ----------------

__global__ __launch_bounds__(256) void k_wprep3(const float* __restrict__ W0, const float* __restrict__ W1,
                                                const float* __restrict__ W2, ushort* __restrict__ wb) {
    int t = blockIdx.x * 256 + threadIdx.x;  // 49152 = 3*128*128
    int m = t >> 14;
    int i = t & 16383;
    const float* W = (m == 0) ? W0 : ((m == 1) ? W1 : W2);
    int k = i >> 7, col = i & 127;
    wb[m * 16384 + col * 128 + k] = (ushort)(bf_round(W[i]) >> 16);
}

// ---------------- MFMA GEMM: C_bf16[N,128] = bn_relu(A)[N,128] @ W ----------------
// IN_BF16 path computes the previous layer's BN scale/shift from stats in LDS (fused bn_fin).
// MFMA operands swapped (W-frag as A, row-frag as B) so D is transposed: lane owns one C-row
// and 4 consecutive C-cols per reg -> shfl-free epilogue with uint2 stores.

template <int IN_BF16>
__global__ __launch_bounds__(256) void k_mm(const void* __restrict__ Ain, const uint4* __restrict__ wb4,
                                            uint* __restrict__ C, int N, const float* __restrict__ stats,
                                            const float* __restrict__ gg, const float* __restrict__ be,
                                            float invN) {
    __shared__ uint4 wl[2048];  // 32KB: idx = col*16 + kk*4 + g, stored at idx ^ ((idx>>4)&7)
    __shared__ float scshs[256];
    const int t = threadIdx.x;
#pragma unroll
    for (int i = 0; i < 8; ++i) {
        int idx = i * 256 + t;
        wl[idx ^ ((idx >> 4) & 7)] = wb4[idx];
    }
    if (IN_BF16 && t < 128) {
        float mean = stats[t] * invN;
        float var = fmaf(-mean, mean, stats[HD + t] * invN);
        float sc = gg[t] * rsqrtf(var + BN_EPS);
        scshs[t] = sc;
        scshs[HD + t] = fmaf(-mean, sc, be[t]);
    }
    __syncthreads();

    const int l = t & 63;
    const int w = t >> 6;
    const int r = l & 15;
    const int g = l >> 4;
    const int rbase = blockIdx.x * 128 + w * 32;

    short8 a[2][4];
#pragma unroll
    for (int tt = 0; tt < 2; ++tt) {
        int row = rbase + tt * 16 + r;
        bool ok = row < N;
#pragma unroll
        for (int kk = 0; kk < 4; ++kk) {
            U4S8 v;
            v.u = make_uint4(0u, 0u, 0u, 0u);
            if (ok) {
                if (IN_BF16) {
                    uint4 ld = ((const uint4*)Ain)[(size_t)row * 16 + kk * 4 + g];
                    float f[8];
                    unpack8(ld, f);
                    const float4 sc0 = *(const float4*)&scshs[(kk * 8 + g * 2) * 4];
                    const float4 sc1 = *(const float4*)&scshs[(kk * 8 + g * 2 + 1) * 4];
                    const float4 sh0 = *(const float4*)&scshs[HD + (kk * 8 + g * 2) * 4];
                    const float4 sh1 = *(const float4*)&scshs[HD + (kk * 8 + g * 2 + 1) * 4];
                    f[0] = fmaxf(fmaf(f[0], sc0.x, sh0.x), 0.f);
                    f[1] = fmaxf(fmaf(f[1], sc0.y, sh0.y), 0.f);
                    f[2] = fmaxf(fmaf(f[2], sc0.z, sh0.z), 0.f);
                    f[3] = fmaxf(fmaf(f[3], sc0.w, sh0.w), 0.f);
                    f[4] = fmaxf(fmaf(f[4], sc1.x, sh1.x), 0.f);
                    f[5] = fmaxf(fmaf(f[5], sc1.y, sh1.y), 0.f);
                    f[6] = fmaxf(fmaf(f[6], sc1.z, sh1.z), 0.f);
                    f[7] = fmaxf(fmaf(f[7], sc1.w, sh1.w), 0.f);
                    v.u.x = pack_bf2(f[0], f[1]);
                    v.u.y = pack_bf2(f[2], f[3]);
                    v.u.z = pack_bf2(f[4], f[5]);
                    v.u.w = pack_bf2(f[6], f[7]);
                } else {
                    const float4* A4 = (const float4*)Ain;
                    float4 x0 = A4[(size_t)row * 32 + kk * 8 + g * 2];
                    float4 x1 = A4[(size_t)row * 32 + kk * 8 + g * 2 + 1];
                    v.u.x = pack_bf2(x0.x, x0.y);
                    v.u.y = pack_bf2(x0.z, x0.w);
                    v.u.z = pack_bf2(x1.x, x1.y);
                    v.u.w = pack_bf2(x1.z, x1.w);
                }
            }
            a[tt][kk] = v.s;
        }
    }

    f32x4 acc[2][8];
#pragma unroll
    for (int tt = 0; tt < 2; ++tt)
#pragma unroll
        for (int c = 0; c < 8; ++c) acc[tt][c] = (f32x4){0.f, 0.f, 0.f, 0.f};

#pragma unroll
    for (int c = 0; c < 8; ++c) {
#pragma unroll
        for (int kk = 0; kk < 4; ++kk) {
            int idx = (c * 16 + r) * 16 + kk * 4 + g;
            U4S8 b;
            b.u = wl[idx ^ ((idx >> 4) & 7)];
            // swapped operands: D layout transposed (lane: C-row = l&15, 4 C-cols = g*4+reg)
            acc[0][c] = __builtin_amdgcn_mfma_f32_16x16x32_bf16(b.s, a[0][kk], acc[0][c], 0, 0, 0);
            acc[1][c] = __builtin_amdgcn_mfma_f32_16x16x32_bf16(b.s, a[1][kk], acc[1][c], 0, 0, 0);
        }
    }

    // epilogue: lane packs its own 4 consecutive cols -> one uint2 store per (tt,c), no shfl
#pragma unroll
    for (int tt = 0; tt < 2; ++tt) {
        int row = rbase + tt * 16 + r;
        if (row < N) {
#pragma unroll
            for (int c = 0; c < 8; ++c) {
                uint2 p;
                p.x = pack_bf2(acc[tt][c][0], acc[tt][c][1]);
                p.y = pack_bf2(acc[tt][c][2], acc[tt][c][3]);
                *(uint2*)&C[(size_t)row * 64 + c * 8 + g * 2] = p;
            }
        }
    }
}

// ---------------- fused aggregation (VERBATIM r6-benched: 84us, VGPR 32, 2048 blocks) ----------------
// wave layout: slot s = lane&15 (features 8s..8s+7, one uint4), quarter q = lane>>4.
// virtual edge 0 = self-loop (w = dinv^2); virtual edges 1..deg = CSR edges.

#define GATHER_BLOCKS 2048

__global__ __launch_bounds__(256) void k_gather(const uint4* __restrict__ hW4, const int* __restrict__ rowptr,
                                                const int* __restrict__ rowend, const int* __restrict__ csr_src,
                                                const float* __restrict__ csr_w, const float* __restrict__ dinv,
                                                const float* __restrict__ bias, uint4* __restrict__ agg4,
                                                float* __restrict__ stats, int N) {
    const int l = threadIdx.x & 63;
    const int s = l & 15;
    const int q = l >> 4;
    const int wv = threadIdx.x >> 6;
    const int wid0 = blockIdx.x * 4 + wv;
    const int wstride = gridDim.x * 4;

    float bj[8];
    {
        const float4 b0 = ((const float4*)bias)[s * 2];
        const float4 b1 = ((const float4*)bias)[s * 2 + 1];
        bj[0] = b0.x; bj[1] = b0.y; bj[2] = b0.z; bj[3] = b0.w;
        bj[4] = b1.x; bj[5] = b1.y; bj[6] = b1.z; bj[7] = b1.w;
    }

    float ssum[8] = {0, 0, 0, 0, 0, 0, 0, 0};
    float ssq[8] = {0, 0, 0, 0, 0, 0, 0, 0};

    for (int n = wid0; n < N; n += wstride) {
        float sw = dinv[n];
        sw *= sw;
        const int rp = rowptr[n];
        const int re = rowend[n];
        const int deg1 = re - rp + 1;  // virtual edges: self + deg

        float a[8];
#pragma unroll
        for (int j = 0; j < 8; ++j) a[j] = (q == 0) ? bj[j] : 0.f;

        // prefetch first virtual edge for this lane group
        int idx = n;
        float w = 0.f;
        {
            int vi = q;
            if (vi == 0) { w = sw; }
            else if (vi < deg1) { int ei = rp + vi - 1; idx = csr_src[ei]; w = csr_w[ei]; }
        }
        int base = 0;
        while (true) {
            uint4 r4 = hW4[(size_t)idx * 16 + s];
            int base2 = base + 4;
            int idx2 = n;
            float w2 = 0.f;
            const bool more = base2 < deg1;
            if (more) {
                int vi = base2 + q;
                if (vi < deg1) { int ei = rp + vi - 1; idx2 = csr_src[ei]; w2 = csr_w[ei]; }
            }
            float f[8];
            unpack8(r4, f);
#pragma unroll
            for (int j = 0; j < 8; ++j) a[j] = fmaf(f[j], w, a[j]);
            if (!more) break;
            base = base2; idx = idx2; w = w2;
        }

        // cross-quarter reduce (4 partials per feature slot)
#pragma unroll
        for (int j = 0; j < 8; ++j) {
            float v = a[j];
            v += __shfl_xor(v, 16);
            v += __shfl_xor(v, 32);
            a[j] = v;
        }
        if (q == 0) {
            uint4 o;
            o.x = pack_bf2(a[0], a[1]);
            o.y = pack_bf2(a[2], a[3]);
            o.z = pack_bf2(a[4], a[5]);
            o.w = pack_bf2(a[6], a[7]);
            agg4[(size_t)n * 16 + s] = o;
        }
#pragma unroll
        for (int j = 0; j < 8; ++j) {
            ssum[j] += a[j];
            ssq[j] = fmaf(a[j], a[j], ssq[j]);
        }
    }

    __shared__ float red[2][4][16][8];
    if (q == 0) {
#pragma unroll
        for (int j = 0; j < 8; ++j) {
            red[0][wv][s][j] = ssum[j];
            red[1][wv][s][j] = ssq[j];
        }
    }
    __syncthreads();
    const int t = threadIdx.x;
    const int f = t & 127, half = t >> 7;
    float v = red[half][0][f >> 3][f & 7] + red[half][1][f >> 3][f & 7] +
              red[half][2][f >> 3][f & 7] + red[half][3][f >> 3][f & 7];
    unsafeAtomicAdd(&stats[half * HD + f], v);
}

// ---------------- decode: 2 queries per wave, 4 rows per load instruction; BN fused from stats ----

__global__ __launch_bounds__(256) void k_decode(const uint4* __restrict__ h4, const float* __restrict__ stats,
                                                const float* __restrict__ gg, const float* __restrict__ be,
                                                float invN, const int* __restrict__ qu,
                                                const int* __restrict__ qv, float* __restrict__ out, int Q) {
    __shared__ float scshs[256];
    const int t = threadIdx.x;
    if (t < 128) {
        float mean = stats[t] * invN;
        float var = fmaf(-mean, mean, stats[HD + t] * invN);
        float sc = gg[t] * rsqrtf(var + BN_EPS);
        scshs[t] = sc;
        scshs[HD + t] = fmaf(-mean, sc, be[t]);
    }
    __syncthreads();

    int tid = blockIdx.x * 256 + t;
    int wid = tid >> 6;
    int l = t & 63;
    int h = l >> 5, r = (l >> 4) & 1, s = l & 15;
    int qi = wid * 2 + h;
    if (qi >= Q) return;
    int node = r ? qv[qi] : qu[qi];
    uint4 row = h4[(size_t)node * 16 + s];

    float sc[8], sh[8];
    {
        const float4 c0 = *(const float4*)&scshs[s * 8];
        const float4 c1 = *(const float4*)&scshs[s * 8 + 4];
        const float4 h0 = *(const float4*)&scshs[HD + s * 8];
        const float4 h1 = *(const float4*)&scshs[HD + s * 8 + 4];
        sc[0] = c0.x; sc[1] = c0.y; sc[2] = c0.z; sc[3] = c0.w;
        sc[4] = c1.x; sc[5] = c1.y; sc[6] = c1.z; sc[7] = c1.w;
        sh[0] = h0.x; sh[1] = h0.y; sh[2] = h0.z; sh[3] = h0.w;
        sh[4] = h1.x; sh[5] = h1.y; sh[6] = h1.z; sh[7] = h1.w;
    }

    float own[8], oth[8];
    unpack8(row, own);
    uint4 p;
    p.x = __shfl_xor((int)row.x, 16);
    p.y = __shfl_xor((int)row.y, 16);
    p.z = __shfl_xor((int)row.z, 16);
    p.w = __shfl_xor((int)row.w, 16);
    unpack8(p, oth);

    float dot = 0.f;
#pragma unroll
    for (int j = 0; j < 8; ++j) {
        float a = fmaf(own[j], sc[j], sh[j]);
        float b = fmaf(oth[j], sc[j], sh[j]);
        dot = fmaf(a, b, dot);
    }
    dot += __shfl_xor(dot, 1);
    dot += __shfl_xor(dot, 2);
    dot += __shfl_xor(dot, 4);
    dot += __shfl_xor(dot, 8);
    if ((l & 31) == 0) out[qi] = dot;
}

// ---------------- launch ----------------

static inline size_t alignup(size_t x) { return (x + 511) & ~(size_t)511; }

extern "C" void kernel_launch(void* const* d_in, const int* in_sizes, int n_in,
                              void* d_out, int out_size, void* d_ws, size_t ws_size,
                              hipStream_t stream) {
    const float* x     = (const float*)d_in[0];
    const float* Wl[3]  = {(const float*)d_in[1], (const float*)d_in[5], (const float*)d_in[9]};
    const float* bl[3]  = {(const float*)d_in[2], (const float*)d_in[6], (const float*)d_in[10]};
    const float* gl[3]  = {(const float*)d_in[3], (const float*)d_in[7], (const float*)d_in[11]};
    const float* bel[3] = {(const float*)d_in[4], (const float*)d_in[8], (const float*)d_in[12]};
    const int* ei  = (const int*)d_in[13];
    const int* eli = (const int*)d_in[14];

    const int N = in_sizes[0] / HD;
    const int E = in_sizes[13] / 2;
    const int Q = in_sizes[14] / 2;
    const int* src = ei;
    const int* dst = ei + E;
    const int* qu = eli;
    const int* qv = eli + Q;
    float* out = (float*)d_out;

    char* ws = (char*)d_ws;
    size_t off = 0;
    float* dinv    = (float*)(ws + off); off = alignup(off + (size_t)N * 4);
    // cnt and stats3 contiguous -> one memset clears both
    int*   cnt     = (int*)(ws + off);
    float* stats3  = (float*)(ws + off + (size_t)N * 4);
    const size_t zbytes = (size_t)N * 4 + 768 * 4;
    off = alignup(off + zbytes);
    int*   rowptr  = (int*)(ws + off);   off = alignup(off + (size_t)N * 4);
    int*   cursor  = (int*)(ws + off);   off = alignup(off + (size_t)N * 4);
    int*   bsum    = (int*)(ws + off);   off = alignup(off + 1024 * 4);
    ushort* wb     = (ushort*)(ws + off); off = alignup(off + 3 * 128 * 128 * 2);
    int*   csr_src = (int*)(ws + off);   off = alignup(off + (size_t)E * 4);
    float* csr_w   = (float*)(ws + off); off = alignup(off + (size_t)E * 4);
    uint*  hB      = (uint*)(ws + off);  off = alignup(off + (size_t)N * HD * 2);  // bf16 gemm out
    uint*  hA      = (uint*)(ws + off);  off = alignup(off + (size_t)N * HD * 2);  // bf16 agg out
    (void)ws_size; (void)n_in; (void)out_size;

    const float invN = 1.0f / (float)N;
    const int NB = (N + 1023) / 1024;
    const int eg = (E + 255) / 256;

    // ---- CSR build + weight prep ----
    hipMemsetAsync(cnt, 0, zbytes, stream);
    k_count<<<eg, 256, 0, stream>>>(dst, cnt, E);
    k_scan_a<<<NB, 256, 0, stream>>>(cnt, bsum, dinv, N);
    k_scan_b<<<1, 256, 0, stream>>>(bsum, NB);
    k_scan_c<<<NB, 256, 0, stream>>>(cnt, bsum, rowptr, cursor, N);
    k_fill<<<eg, 256, 0, stream>>>(src, dst, dinv, cursor, csr_src, csr_w, E);
    k_wprep3<<<192, 256, 0, stream>>>(Wl[0], Wl[1], Wl[2], wb);

    // ---- 3 GCN layers ----
    const int mmg = (N + 127) / 128;
    for (int l = 0; l < 3; ++l) {
        const uint4* wbl = (const uint4*)(wb + (size_t)l * 16384);
        if (l == 0)
            k_mm<0><<<mmg, 256, 0, stream>>>(x, wbl, hB, N, nullptr, nullptr, nullptr, 0.f);
        else
            k_mm<1><<<mmg, 256, 0, stream>>>(hA, wbl, hB, N, stats3 + (l - 1) * 256,
                                             gl[l - 1], bel[l - 1], invN);
        k_gather<<<GATHER_BLOCKS, 256, 0, stream>>>((const uint4*)hB, rowptr, cursor, csr_src, csr_w,
                                                    dinv, bl[l], (uint4*)hA, stats3 + l * 256, N);
    }

    const int dw = (Q + 1) / 2;  // decode waves (2 queries each)
    k_decode<<<(dw + 3) / 4, 256, 0, stream>>>((const uint4*)hA, stats3 + 512, gl[2], bel[2], invN,
                                               qu, qv, out, Q);
}

// Round 13
// 422.681 us; speedup vs baseline: 1.2741x; 1.0075x over previous
//
#include <hip/hip_runtime.h>

#define HD 128
#define BN_EPS 1e-5f

typedef unsigned int uint;
typedef unsigned short ushort;
typedef __attribute__((ext_vector_type(8))) short short8;
typedef __attribute__((ext_vector_type(4))) float f32x4;

union U4S8 { uint4 u; short8 s; };

// bf16x2 packed in a uint: lo half = even feature, hi half = odd feature
__device__ __forceinline__ float bf_lo(uint u) { return __uint_as_float(u << 16); }
__device__ __forceinline__ float bf_hi(uint u) { return __uint_as_float(u & 0xffff0000u); }
__device__ __forceinline__ uint bf_round(float f) {  // RNE to bf16 bits (in high 16)
    uint u = __float_as_uint(f);
    return (u + 0x7fffu + ((u >> 16) & 1u)) & 0xffff0000u;
}
__device__ __forceinline__ uint pack_bf2(float a, float b) {
    return (bf_round(a) >> 16) | bf_round(b);
}
__device__ __forceinline__ void unpack8(uint4 u, float* f) {
    f[0] = bf_lo(u.x); f[1] = bf_hi(u.x);
    f[2] = bf_lo(u.y); f[3] = bf_hi(u.y);
    f[4] = bf_lo(u.z); f[5] = bf_hi(u.z);
    f[6] = bf_lo(u.w); f[7] = bf_hi(u.w);
}

// ---------------- CSR build ----------------

// count edges per dst; blocks 0..191 also prep W (transpose + bf16 round, all 3 layers)
__global__ __launch_bounds__(256) void k_count(const int* __restrict__ dst, int* __restrict__ cnt, int E,
                                               const float* __restrict__ W0, const float* __restrict__ W1,
                                               const float* __restrict__ W2, ushort* __restrict__ wb) {
    int e = blockIdx.x * 256 + threadIdx.x;
    if (e < E) atomicAdd(&cnt[dst[e]], 1);
    if (e < 49152) {  // 3*128*128: wb[l][col][k] = bf16(W_l[k][col])
        int m = e >> 14;
        int i = e & 16383;
        const float* W = (m == 0) ? W0 : ((m == 1) ? W1 : W2);
        int k = i >> 7, col = i & 127;
        wb[m * 16384 + col * 128 + k] = (ushort)(bf_round(W[i]) >> 16);
    }
}

// block partial sums over 1024-element chunks; also computes dinv
__global__ __launch_bounds__(256) void k_scan_a(const int* __restrict__ cnt, int* __restrict__ bsum,
                                                float* __restrict__ dinv, int N) {
    __shared__ int s[256];
    int base = blockIdx.x * 1024 + threadIdx.x * 4;
    int v = 0;
#pragma unroll
    for (int j = 0; j < 4; ++j) {
        int idx = base + j;
        if (idx < N) {
            int c = cnt[idx];
            v += c;
            dinv[idx] = rsqrtf((float)c + 1.0f);
        }
    }
    s[threadIdx.x] = v;
    __syncthreads();
    for (int o = 128; o; o >>= 1) {
        if (threadIdx.x < (unsigned)o) s[threadIdx.x] += s[threadIdx.x + o];
        __syncthreads();
    }
    if (threadIdx.x == 0) bsum[blockIdx.x] = s[0];
}

// per-chunk exclusive scan; block offset computed in-block from raw bsum (scan_b eliminated)
__global__ __launch_bounds__(256) void k_scan_c(const int* __restrict__ cnt, const int* __restrict__ bsum,
                                                int* __restrict__ rowptr, int* __restrict__ cursor, int N) {
    __shared__ int s[256];
    __shared__ int boff_s;
    const int t = threadIdx.x;

    // block offset = sum of bsum[0..blockIdx) (NB <= 256 chunks here; grid-safe loop)
    int bv = 0;
    for (int i = t; i < blockIdx.x; i += 256) bv += bsum[i];
    s[t] = bv;
    __syncthreads();
    for (int o = 128; o; o >>= 1) {
        if (t < (unsigned)o) s[t] += s[t + o];
        __syncthreads();
    }
    if (t == 0) boff_s = s[0];
    __syncthreads();
    const int boff = boff_s;
    __syncthreads();

    int base = blockIdx.x * 1024 + t * 4;
    int v0 = 0, v1 = 0, v2 = 0, v3 = 0;
    if (base + 0 < N) v0 = cnt[base + 0];
    if (base + 1 < N) v1 = cnt[base + 1];
    if (base + 2 < N) v2 = cnt[base + 2];
    if (base + 3 < N) v3 = cnt[base + 3];
    int ts = v0 + v1 + v2 + v3;
    s[t] = ts;
    __syncthreads();
    for (int o = 1; o < 256; o <<= 1) {
        int add = (t >= o) ? s[t - o] : 0;
        __syncthreads();
        s[t] += add;
        __syncthreads();
    }
    int excl = s[t] - ts + boff;
    int p0 = excl, p1 = excl + v0, p2 = excl + v0 + v1, p3 = excl + v0 + v1 + v2;
    if (base + 0 < N) { rowptr[base + 0] = p0; cursor[base + 0] = p0; }
    if (base + 1 < N) { rowptr[base + 1] = p1; cursor[base + 1] = p1; }
    if (base + 2 < N) { rowptr[base + 2] = p2; cursor[base + 2] = p2; }
    if (base + 3 < N) { rowptr[base + 3] = p3; cursor[base + 3] = p3; }
}

// cursor starts as copy of rowptr; fill bumps it to row end (verbatim r6)
__global__ __launch_bounds__(256) void k_fill(const int* __restrict__ src, const int* __restrict__ dst,
                                              const float* __restrict__ dinv, int* __restrict__ cursor,
                                              int* __restrict__ csr_src, float* __restrict__ csr_w, int E) {
    int e = blockIdx.x * 256 + threadIdx.x;
    if (e >= E) return;
    int s = src[e], d = dst[e];
    int pos = atomicAdd(&cursor[d], 1);
    csr_src[pos] = s;
    csr_w[pos] = dinv[s] * dinv[d];
}

// ---------------- MFMA GEMM: C_bf16[N,128] = bn_relu(A)[N,128] @ W ----------------
// IN_BF16 path computes the previous layer's BN scale/shift from stats in LDS (fused bn_fin).
// MFMA operands swapped (W-frag as A, row-frag as B) so D is transposed: lane owns one C-row
// and 4 consecutive C-cols per reg -> shfl-free epilogue with uint2 stores.

template <int IN_BF16>
__global__ __launch_bounds__(256) void k_mm(const void* __restrict__ Ain, const uint4* __restrict__ wb4,
                                            uint* __restrict__ C, int N, const float* __restrict__ stats,
                                            const float* __restrict__ gg, const float* __restrict__ be,
                                            float invN) {
    __shared__ uint4 wl[2048];  // 32KB: idx = col*16 + kk*4 + g, stored at idx ^ ((idx>>4)&7)
    __shared__ float scshs[256];
    const int t = threadIdx.x;
#pragma unroll
    for (int i = 0; i < 8; ++i) {
        int idx = i * 256 + t;
        wl[idx ^ ((idx >> 4) & 7)] = wb4[idx];
    }
    if (IN_BF16 && t < 128) {
        float mean = stats[t] * invN;
        float var = fmaf(-mean, mean, stats[HD + t] * invN);
        float sc = gg[t] * rsqrtf(var + BN_EPS);
        scshs[t] = sc;
        scshs[HD + t] = fmaf(-mean, sc, be[t]);
    }
    __syncthreads();

    const int l = t & 63;
    const int w = t >> 6;
    const int r = l & 15;
    const int g = l >> 4;
    const int rbase = blockIdx.x * 128 + w * 32;

    short8 a[2][4];
#pragma unroll
    for (int tt = 0; tt < 2; ++tt) {
        int row = rbase + tt * 16 + r;
        bool ok = row < N;
#pragma unroll
        for (int kk = 0; kk < 4; ++kk) {
            U4S8 v;
            v.u = make_uint4(0u, 0u, 0u, 0u);
            if (ok) {
                if (IN_BF16) {
                    uint4 ld = ((const uint4*)Ain)[(size_t)row * 16 + kk * 4 + g];
                    float f[8];
                    unpack8(ld, f);
                    const float4 sc0 = *(const float4*)&scshs[(kk * 8 + g * 2) * 4];
                    const float4 sc1 = *(const float4*)&scshs[(kk * 8 + g * 2 + 1) * 4];
                    const float4 sh0 = *(const float4*)&scshs[HD + (kk * 8 + g * 2) * 4];
                    const float4 sh1 = *(const float4*)&scshs[HD + (kk * 8 + g * 2 + 1) * 4];
                    f[0] = fmaxf(fmaf(f[0], sc0.x, sh0.x), 0.f);
                    f[1] = fmaxf(fmaf(f[1], sc0.y, sh0.y), 0.f);
                    f[2] = fmaxf(fmaf(f[2], sc0.z, sh0.z), 0.f);
                    f[3] = fmaxf(fmaf(f[3], sc0.w, sh0.w), 0.f);
                    f[4] = fmaxf(fmaf(f[4], sc1.x, sh1.x), 0.f);
                    f[5] = fmaxf(fmaf(f[5], sc1.y, sh1.y), 0.f);
                    f[6] = fmaxf(fmaf(f[6], sc1.z, sh1.z), 0.f);
                    f[7] = fmaxf(fmaf(f[7], sc1.w, sh1.w), 0.f);
                    v.u.x = pack_bf2(f[0], f[1]);
                    v.u.y = pack_bf2(f[2], f[3]);
                    v.u.z = pack_bf2(f[4], f[5]);
                    v.u.w = pack_bf2(f[6], f[7]);
                } else {
                    const float4* A4 = (const float4*)Ain;
                    float4 x0 = A4[(size_t)row * 32 + kk * 8 + g * 2];
                    float4 x1 = A4[(size_t)row * 32 + kk * 8 + g * 2 + 1];
                    v.u.x = pack_bf2(x0.x, x0.y);
                    v.u.y = pack_bf2(x0.z, x0.w);
                    v.u.z = pack_bf2(x1.x, x1.y);
                    v.u.w = pack_bf2(x1.z, x1.w);
                }
            }
            a[tt][kk] = v.s;
        }
    }

    f32x4 acc[2][8];
#pragma unroll
    for (int tt = 0; tt < 2; ++tt)
#pragma unroll
        for (int c = 0; c < 8; ++c) acc[tt][c] = (f32x4){0.f, 0.f, 0.f, 0.f};

#pragma unroll
    for (int c = 0; c < 8; ++c) {
#pragma unroll
        for (int kk = 0; kk < 4; ++kk) {
            int idx = (c * 16 + r) * 16 + kk * 4 + g;
            U4S8 b;
            b.u = wl[idx ^ ((idx >> 4) & 7)];
            // swapped operands: D layout transposed (lane: C-row = l&15, 4 C-cols = g*4+reg)
            acc[0][c] = __builtin_amdgcn_mfma_f32_16x16x32_bf16(b.s, a[0][kk], acc[0][c], 0, 0, 0);
            acc[1][c] = __builtin_amdgcn_mfma_f32_16x16x32_bf16(b.s, a[1][kk], acc[1][c], 0, 0, 0);
        }
    }

    // epilogue: lane packs its own 4 consecutive cols -> one uint2 store per (tt,c), no shfl
#pragma unroll
    for (int tt = 0; tt < 2; ++tt) {
        int row = rbase + tt * 16 + r;
        if (row < N) {
#pragma unroll
            for (int c = 0; c < 8; ++c) {
                uint2 p;
                p.x = pack_bf2(acc[tt][c][0], acc[tt][c][1]);
                p.y = pack_bf2(acc[tt][c][2], acc[tt][c][3]);
                *(uint2*)&C[(size_t)row * 64 + c * 8 + g * 2] = p;
            }
        }
    }
}

// ---------------- fused aggregation (VERBATIM r6-benched: 84us, VGPR 32, 2048 blocks) ----------------
// wave layout: slot s = lane&15 (features 8s..8s+7, one uint4), quarter q = lane>>4.
// virtual edge 0 = self-loop (w = dinv^2); virtual edges 1..deg = CSR edges.

#define GATHER_BLOCKS 2048

__global__ __launch_bounds__(256) void k_gather(const uint4* __restrict__ hW4, const int* __restrict__ rowptr,
                                                const int* __restrict__ rowend, const int* __restrict__ csr_src,
                                                const float* __restrict__ csr_w, const float* __restrict__ dinv,
                                                const float* __restrict__ bias, uint4* __restrict__ agg4,
                                                float* __restrict__ stats, int N) {
    const int l = threadIdx.x & 63;
    const int s = l & 15;
    const int q = l >> 4;
    const int wv = threadIdx.x >> 6;
    const int wid0 = blockIdx.x * 4 + wv;
    const int wstride = gridDim.x * 4;

    float bj[8];
    {
        const float4 b0 = ((const float4*)bias)[s * 2];
        const float4 b1 = ((const float4*)bias)[s * 2 + 1];
        bj[0] = b0.x; bj[1] = b0.y; bj[2] = b0.z; bj[3] = b0.w;
        bj[4] = b1.x; bj[5] = b1.y; bj[6] = b1.z; bj[7] = b1.w;
    }

    float ssum[8] = {0, 0, 0, 0, 0, 0, 0, 0};
    float ssq[8] = {0, 0, 0, 0, 0, 0, 0, 0};

    for (int n = wid0; n < N; n += wstride) {
        float sw = dinv[n];
        sw *= sw;
        const int rp = rowptr[n];
        const int re = rowend[n];
        const int deg1 = re - rp + 1;  // virtual edges: self + deg

        float a[8];
#pragma unroll
        for (int j = 0; j < 8; ++j) a[j] = (q == 0) ? bj[j] : 0.f;

        // prefetch first virtual edge for this lane group
        int idx = n;
        float w = 0.f;
        {
            int vi = q;
            if (vi == 0) { w = sw; }
            else if (vi < deg1) { int ei = rp + vi - 1; idx = csr_src[ei]; w = csr_w[ei]; }
        }
        int base = 0;
        while (true) {
            uint4 r4 = hW4[(size_t)idx * 16 + s];
            int base2 = base + 4;
            int idx2 = n;
            float w2 = 0.f;
            const bool more = base2 < deg1;
            if (more) {
                int vi = base2 + q;
                if (vi < deg1) { int ei = rp + vi - 1; idx2 = csr_src[ei]; w2 = csr_w[ei]; }
            }
            float f[8];
            unpack8(r4, f);
#pragma unroll
            for (int j = 0; j < 8; ++j) a[j] = fmaf(f[j], w, a[j]);
            if (!more) break;
            base = base2; idx = idx2; w = w2;
        }

        // cross-quarter reduce (4 partials per feature slot)
#pragma unroll
        for (int j = 0; j < 8; ++j) {
            float v = a[j];
            v += __shfl_xor(v, 16);
            v += __shfl_xor(v, 32);
            a[j] = v;
        }
        if (q == 0) {
            uint4 o;
            o.x = pack_bf2(a[0], a[1]);
            o.y = pack_bf2(a[2], a[3]);
            o.z = pack_bf2(a[4], a[5]);
            o.w = pack_bf2(a[6], a[7]);
            agg4[(size_t)n * 16 + s] = o;
        }
#pragma unroll
        for (int j = 0; j < 8; ++j) {
            ssum[j] += a[j];
            ssq[j] = fmaf(a[j], a[j], ssq[j]);
        }
    }

    __shared__ float red[2][4][16][8];
    if (q == 0) {
#pragma unroll
        for (int j = 0; j < 8; ++j) {
            red[0][wv][s][j] = ssum[j];
            red[1][wv][s][j] = ssq[j];
        }
    }
    __syncthreads();
    const int t = threadIdx.x;
    const int f = t & 127, half = t >> 7;
    float v = red[half][0][f >> 3][f & 7] + red[half][1][f >> 3][f & 7] +
              red[half][2][f >> 3][f & 7] + red[half][3][f >> 3][f & 7];
    unsafeAtomicAdd(&stats[half * HD + f], v);
}

// ---------------- decode: 2 queries per wave, 4 rows per load instruction; BN fused from stats ----

__global__ __launch_bounds__(256) void k_decode(const uint4* __restrict__ h4, const float* __restrict__ stats,
                                                const float* __restrict__ gg, const float* __restrict__ be,
                                                float invN, const int* __restrict__ qu,
                                                const int* __restrict__ qv, float* __restrict__ out, int Q) {
    __shared__ float scshs[256];
    const int t = threadIdx.x;
    if (t < 128) {
        float mean = stats[t] * invN;
        float var = fmaf(-mean, mean, stats[HD + t] * invN);
        float sc = gg[t] * rsqrtf(var + BN_EPS);
        scshs[t] = sc;
        scshs[HD + t] = fmaf(-mean, sc, be[t]);
    }
    __syncthreads();

    int tid = blockIdx.x * 256 + t;
    int wid = tid >> 6;
    int l = t & 63;
    int h = l >> 5, r = (l >> 4) & 1, s = l & 15;
    int qi = wid * 2 + h;
    if (qi >= Q) return;
    int node = r ? qv[qi] : qu[qi];
    uint4 row = h4[(size_t)node * 16 + s];

    float sc[8], sh[8];
    {
        const float4 c0 = *(const float4*)&scshs[s * 8];
        const float4 c1 = *(const float4*)&scshs[s * 8 + 4];
        const float4 h0 = *(const float4*)&scshs[HD + s * 8];
        const float4 h1 = *(const float4*)&scshs[HD + s * 8 + 4];
        sc[0] = c0.x; sc[1] = c0.y; sc[2] = c0.z; sc[3] = c0.w;
        sc[4] = c1.x; sc[5] = c1.y; sc[6] = c1.z; sc[7] = c1.w;
        sh[0] = h0.x; sh[1] = h0.y; sh[2] = h0.z; sh[3] = h0.w;
        sh[4] = h1.x; sh[5] = h1.y; sh[6] = h1.z; sh[7] = h1.w;
    }

    float own[8], oth[8];
    unpack8(row, own);
    uint4 p;
    p.x = __shfl_xor((int)row.x, 16);
    p.y = __shfl_xor((int)row.y, 16);
    p.z = __shfl_xor((int)row.z, 16);
    p.w = __shfl_xor((int)row.w, 16);
    unpack8(p, oth);

    float dot = 0.f;
#pragma unroll
    for (int j = 0; j < 8; ++j) {
        float a = fmaf(own[j], sc[j], sh[j]);
        float b = fmaf(oth[j], sc[j], sh[j]);
        dot = fmaf(a, b, dot);
    }
    dot += __shfl_xor(dot, 1);
    dot += __shfl_xor(dot, 2);
    dot += __shfl_xor(dot, 4);
    dot += __shfl_xor(dot, 8);
    if ((l & 31) == 0) out[qi] = dot;
}

// ---------------- launch ----------------

static inline size_t alignup(size_t x) { return (x + 511) & ~(size_t)511; }

extern "C" void kernel_launch(void* const* d_in, const int* in_sizes, int n_in,
                              void* d_out, int out_size, void* d_ws, size_t ws_size,
                              hipStream_t stream) {
    const float* x     = (const float*)d_in[0];
    const float* Wl[3]  = {(const float*)d_in[1], (const float*)d_in[5], (const float*)d_in[9]};
    const float* bl[3]  = {(const float*)d_in[2], (const float*)d_in[6], (const float*)d_in[10]};
    const float* gl[3]  = {(const float*)d_in[3], (const float*)d_in[7], (const float*)d_in[11]};
    const float* bel[3] = {(const float*)d_in[4], (const float*)d_in[8], (const float*)d_in[12]};
    const int* ei  = (const int*)d_in[13];
    const int* eli = (const int*)d_in[14];

    const int N = in_sizes[0] / HD;
    const int E = in_sizes[13] / 2;
    const int Q = in_sizes[14] / 2;
    const int* src = ei;
    const int* dst = ei + E;
    const int* qu = eli;
    const int* qv = eli + Q;
    float* out = (float*)d_out;

    char* ws = (char*)d_ws;
    size_t off = 0;
    float* dinv    = (float*)(ws + off); off = alignup(off + (size_t)N * 4);
    // cnt and stats3 contiguous -> one memset clears both
    int*   cnt     = (int*)(ws + off);
    float* stats3  = (float*)(ws + off + (size_t)N * 4);
    const size_t zbytes = (size_t)N * 4 + 768 * 4;
    off = alignup(off + zbytes);
    int*   rowptr  = (int*)(ws + off);   off = alignup(off + (size_t)N * 4);
    int*   cursor  = (int*)(ws + off);   off = alignup(off + (size_t)N * 4);
    int*   bsum    = (int*)(ws + off);   off = alignup(off + 1024 * 4);
    ushort* wb     = (ushort*)(ws + off); off = alignup(off + 3 * 128 * 128 * 2);
    int*   csr_src = (int*)(ws + off);   off = alignup(off + (size_t)E * 4);
    float* csr_w   = (float*)(ws + off); off = alignup(off + (size_t)E * 4);
    uint*  hB      = (uint*)(ws + off);  off = alignup(off + (size_t)N * HD * 2);  // bf16 gemm out
    uint*  hA      = (uint*)(ws + off);  off = alignup(off + (size_t)N * HD * 2);  // bf16 agg out
    (void)ws_size; (void)n_in; (void)out_size;

    const float invN = 1.0f / (float)N;
    const int NB = (N + 1023) / 1024;
    const int eg = (E + 255) / 256;

    // ---- CSR build + weight prep (wprep folded into count; scan_b folded into scan_c) ----
    hipMemsetAsync(cnt, 0, zbytes, stream);
    k_count<<<eg, 256, 0, stream>>>(dst, cnt, E, Wl[0], Wl[1], Wl[2], wb);
    k_scan_a<<<NB, 256, 0, stream>>>(cnt, bsum, dinv, N);
    k_scan_c<<<NB, 256, 0, stream>>>(cnt, bsum, rowptr, cursor, N);
    k_fill<<<eg, 256, 0, stream>>>(src, dst, dinv, cursor, csr_src, csr_w, E);

    // ---- 3 GCN layers ----
    const int mmg = (N + 127) / 128;
    for (int l = 0; l < 3; ++l) {
        const uint4* wbl = (const uint4*)(wb + (size_t)l * 16384);
        if (l == 0)
            k_mm<0><<<mmg, 256, 0, stream>>>(x, wbl, hB, N, nullptr, nullptr, nullptr, 0.f);
        else
            k_mm<1><<<mmg, 256, 0, stream>>>(hA, wbl, hB, N, stats3 + (l - 1) * 256,
                                             gl[l - 1], bel[l - 1], invN);
        k_gather<<<GATHER_BLOCKS, 256, 0, stream>>>((const uint4*)hB, rowptr, cursor, csr_src, csr_w,
                                                    dinv, bl[l], (uint4*)hA, stats3 + l * 256, N);
    }

    const int dw = (Q + 1) / 2;  // decode waves (2 queries each)
    k_decode<<<(dw + 3) / 4, 256, 0, stream>>>((const uint4*)hA, stats3 + 512, gl[2], bel[2], invN,
                                               qu, qv, out, Q);
}